// Round 8
// baseline (239.371 us; speedup 1.0000x reference)
//
#include <hip/hip_runtime.h>

#define DCOLS 256
#define RB 128               // rows per row-bin
#define NBINP 2048           // padded sub-bin count (actual 2*782=1564)
#define MAT_OFF 16384
#define MAT_CAP (4u<<20)     // u16 mat: nblk(<=1024) * 2048 * 2B = 4 MB max
#define PAIRS_OFF (MAT_OFF + MAT_CAP)
#define BLK4 1024            // int4 per sub-chunk (4096 elements)
#define SUBS 4
#define CHUNK4 (BLK4 * SUBS) // 16384 elements per block

typedef unsigned int u32;
typedef unsigned short u16;
typedef unsigned long long u64;

// transposed LDS hist mapping to avoid 8-stride bank conflicts in the scan read
__device__ __forceinline__ u32 hmap(u32 bin) { return ((bin & 7u) << 8) | (bin >> 3); }

// ---------------- fallback path ----------------
__global__ void copy_f4(const float4* __restrict__ src, float4* __restrict__ dst, int n4) {
    int i = blockIdx.x * blockDim.x + threadIdx.x;
    int stride = gridDim.x * blockDim.x;
    for (; i < n4; i += stride) dst[i] = src[i];
}

__global__ void scatter_add4(const int4* __restrict__ index,
                             const float4* __restrict__ upd,
                             float* __restrict__ out, int n4) {
    int i = blockIdx.x * blockDim.x + threadIdx.x;
    int stride = gridDim.x * blockDim.x;
    for (; i < n4; i += stride) {
        int4 idx  = index[i];
        float4 u  = upd[i];
        int j = (i << 2) & (DCOLS - 1);
        atomicAdd(&out[idx.x * DCOLS + j + 0], u.x);
        atomicAdd(&out[idx.y * DCOLS + j + 1], u.y);
        atomicAdd(&out[idx.z * DCOLS + j + 2], u.z);
        atomicAdd(&out[idx.w * DCOLS + j + 3], u.w);
    }
}

// ---------------- K1: per-block sub-bin histogram -> mat16[blk][bin] ----------
__global__ void __launch_bounds__(256) hist_blocks(const int4* __restrict__ idx4,
                                                   u16* __restrict__ mat, int n4) {
    __shared__ u32 hist[NBINP];
    int t = threadIdx.x;
    int b0 = blockIdx.x * CHUNK4;
    u32 hb = (u32)((t >> 5) & 1);   // col-half bit, uniform per thread
    for (int i = t; i < NBINP; i += 256) hist[i] = 0;
    __syncthreads();
#pragma unroll
    for (int k = 0; k < 16; ++k) {
        int p = b0 + t + 256 * k;
        if (p < n4) {
            int4 v = idx4[p];
            atomicAdd(&hist[(((u32)v.x) >> 7) * 2 + hb], 1u);
            atomicAdd(&hist[(((u32)v.y) >> 7) * 2 + hb], 1u);
            atomicAdd(&hist[(((u32)v.z) >> 7) * 2 + hb], 1u);
            atomicAdd(&hist[(((u32)v.w) >> 7) * 2 + hb], 1u);
        }
    }
    __syncthreads();
    u32 base = (u32)blockIdx.x * NBINP;
    for (int i = t; i < NBINP; i += 256) mat[base + i] = (u16)hist[i];
}

// ---------------- K2: one wave per sub-bin, exclusive scan over blocks --------
__global__ void __launch_bounds__(64) scan_blocks(u16* __restrict__ mat,
                                                  u32* __restrict__ total, int nblk) {
    int bin = blockIdx.x;
    int lane = threadIdx.x;
    u32 carry = 0;
    int rounds = (nblk + 63) / 64;
    for (int r = 0; r < rounds; ++r) {
        int blk = r * 64 + lane;
        u32 v = (blk < nblk) ? (u32)mat[(u32)blk * NBINP + bin] : 0u;
        u32 incl = v;
#pragma unroll
        for (int d = 1; d < 64; d <<= 1) {
            u32 y = __shfl_up(incl, (unsigned)d, 64);
            if (lane >= d) incl += y;
        }
        if (blk < nblk) mat[(u32)blk * NBINP + bin] = (u16)(carry + incl - v);
        carry += (u32)__shfl(incl, 63, 64);
    }
    if (lane == 0) total[bin] = carry;
}

// ---------------- K2b: exclusive scan of 2048 sub-bin totals ------------------
__global__ void scan_binbases(const u32* __restrict__ total, u32* __restrict__ start) {
    __shared__ u32 tmp[1024];
    int t = threadIdx.x;
    u32 a = total[2 * t], b = total[2 * t + 1];
    u32 p = a + b;
    tmp[t] = p;
    __syncthreads();
    for (int off = 1; off < 1024; off <<= 1) {
        u32 x = (t >= off) ? tmp[t - off] : 0u;
        __syncthreads();
        tmp[t] += x;
        __syncthreads();
    }
    u32 e = tmp[t] - p;
    start[2 * t] = e;
    start[2 * t + 1] = e + a;
}

// ---------------- K3: deterministic scatter (no global atomics) ---------------
// LDS: hist 8K + basep 8K + excl16 4K + stage 32K ~= 52.3 KB -> 3 blocks/CU
__global__ void __launch_bounds__(256, 3) scatter_det2(const int4* __restrict__ idx4,
                                                       const float4* __restrict__ upd4,
                                                       const u16* __restrict__ mat,
                                                       const u32* __restrict__ start,
                                                       u64* __restrict__ pairs, int n4) {
    __shared__ u32 hist[NBINP];     // transposed-map counts, then staging cursors
    __shared__ u32 basep[NBINP];    // absolute dest base per sub-bin
    __shared__ u16 excl16[NBINP];   // per-sub exclusive prefix within stage
    __shared__ u32 wtot[4];
    __shared__ u64 stage[4096];     // 32 KB

    int t = threadIdx.x;
    int lane = t & 63, wid = t >> 6;
    int b0 = blockIdx.x * CHUNK4;
    u32 mbase = (u32)blockIdx.x * NBINP;
    u32 hb = (u32)((t >> 5) & 1);

    for (int i = t; i < NBINP; i += 256) basep[i] = start[i] + (u32)mat[mbase + i];

    int4 iv[4]; float4 uv[4]; int4 ivn[4]; float4 uvn[4];
#pragma unroll
    for (int k = 0; k < 4; ++k) {
        int p = b0 + t + 256 * k;
        if (p < n4) { iv[k] = idx4[p]; uv[k] = upd4[p]; }
    }

    for (int s = 0; s < SUBS; ++s) {
        int sbase = b0 + s * BLK4;
        for (int i = t; i < NBINP; i += 256) hist[i] = 0;
        __syncthreads();
#pragma unroll
        for (int k = 0; k < 4; ++k) {
            int p = sbase + t + 256 * k;
            if (p < n4) {
                atomicAdd(&hist[hmap((((u32)iv[k].x) >> 7) * 2 + hb)], 1u);
                atomicAdd(&hist[hmap((((u32)iv[k].y) >> 7) * 2 + hb)], 1u);
                atomicAdd(&hist[hmap((((u32)iv[k].z) >> 7) * 2 + hb)], 1u);
                atomicAdd(&hist[hmap((((u32)iv[k].w) >> 7) * 2 + hb)], 1u);
            }
        }
        __syncthreads();
        // prefetch next sub's data (latency hides under scan+stage)
        if (s < SUBS - 1) {
#pragma unroll
            for (int k = 0; k < 4; ++k) {
                int p = sbase + BLK4 + t + 256 * k;
                if (p < n4) { ivn[k] = idx4[p]; uvn[k] = upd4[p]; }
            }
        }
        // exclusive scan: thread t owns sub-bins 8t..8t+7 (transposed reads)
        u32 c[8], tsum = 0;
#pragma unroll
        for (int j = 0; j < 8; ++j) { c[j] = hist[(u32)(j << 8) | (u32)t]; tsum += c[j]; }
        u32 incl = tsum;
#pragma unroll
        for (int d = 1; d < 64; d <<= 1) {
            u32 y = __shfl_up(incl, (unsigned)d, 64);
            if (lane >= d) incl += y;
        }
        if (lane == 63) wtot[wid] = incl;
        __syncthreads();
        u32 woff = 0;
#pragma unroll
        for (int w = 0; w < 4; ++w) woff += (w < wid) ? wtot[w] : 0u;
        u32 e = woff + incl - tsum;
#pragma unroll
        for (int j = 0; j < 8; ++j) {
            u32 bin = 8u * (u32)t + (u32)j;
            excl16[bin] = (u16)e;
            hist[(u32)(j << 8) | (u32)t] = e;   // staging cursor
            e += c[j];
        }
        __syncthreads();
        // stage bin-sorted
        u32 colbase = (4u * (u32)t) & 255u;
#pragma unroll
        for (int k = 0; k < 4; ++k) {
            int p = sbase + t + 256 * k;
            if (p >= n4) continue;
            int rows[4] = {iv[k].x, iv[k].y, iv[k].z, iv[k].w};
            float vals[4] = {uv[k].x, uv[k].y, uv[k].z, uv[k].w};
#pragma unroll
            for (int cc = 0; cc < 4; ++cc) {
                u32 row = (u32)rows[cc];
                u32 slot = atomicAdd(&hist[hmap((row >> 7) * 2 + hb)], 1u);
                stage[slot] = ((u64)__float_as_uint(vals[cc]) << 32)
                            | ((u64)row << 8) | (u64)(colbase + (u32)cc);
            }
        }
        __syncthreads();
        // coalesced flush to exact destinations
        int sv = n4 - sbase; if (sv > BLK4) sv = BLK4; if (sv < 0) sv = 0;
        int scount = 4 * sv;
        for (int i = t; i < scount; i += 256) {
            u64 pr = stage[i];
            u32 rc  = (u32)pr & 0x1ffffffu;   // row<<8 | col8
            u32 row = rc >> 8;
            u32 col8 = rc & 255u;
            u32 bin = (row >> 7) * 2 + ((col8 >> 7) & 1u);
            u32 d = basep[bin] + ((u32)i - (u32)excl16[bin]);
            u32 key = ((row & 127u) << 8) | col8;
            pairs[d] = (pr & 0xffffffff00000000ull) | (u64)key;
        }
        __syncthreads();
        // advance bases (hist holds end cursors)
        for (int b = t; b < NBINP; b += 256)
            basep[b] += hist[hmap((u32)b)] - (u32)excl16[b];
        if (s < SUBS - 1) {
#pragma unroll
            for (int k = 0; k < 4; ++k) { iv[k] = ivn[k]; uv[k] = uvn[k]; }
        }
        __syncthreads();
    }
}

// ---------------- K4: apply, one block per sub-bin, pairs read once -----------
#define ACC_P(p) { u32 k_ = (u32)(p); \
    atomicAdd(&acc[((k_ >> 8) & 127u) * 128u + (k_ & 127u)], \
              __uint_as_float((u32)((p) >> 32))); }

__global__ void __launch_bounds__(1024, 2) apply_full(const float4* __restrict__ self4,
                                                      const u64* __restrict__ pairs,
                                                      const u32* __restrict__ start,
                                                      const u32* __restrict__ total,
                                                      float4* __restrict__ out4, int nrows) {
    __shared__ float acc[RB * 128];   // 64 KB
    int t = threadIdx.x;
    int sb = blockIdx.x;              // sub-bin
    int bin = sb >> 1;
    u32 half = (u32)(sb & 1);
    float4* acc4 = (float4*)acc;
    for (int i = t; i < RB * 32; i += 1024) acc4[i] = make_float4(0.f, 0.f, 0.f, 0.f);
    __syncthreads();

    u32 s = start[sb], e = s + total[sb];
    u32 i = s + (u32)t;
    for (; i + 3072u < e; i += 4096u) {
        u64 p0 = pairs[i];
        u64 p1 = pairs[i + 1024u];
        u64 p2 = pairs[i + 2048u];
        u64 p3 = pairs[i + 3072u];
        ACC_P(p0); ACC_P(p1); ACC_P(p2); ACC_P(p3);
    }
    for (; i < e; i += 1024u) { u64 p0 = pairs[i]; ACC_P(p0); }
    __syncthreads();

    int r0 = bin * RB;
    int nr = nrows - r0; if (nr > RB) nr = RB;
    int tot4 = nr * 32;
    for (int i2 = t; i2 < tot4; i2 += 1024) {
        int r = i2 >> 5, c4 = i2 & 31;
        long g = (long)(r0 + r) * 64 + (long)(half * 32u) + c4;
        float4 a = self4[g];
        float4 c = acc4[(r << 5) + c4];
        a.x += c.x; a.y += c.y; a.z += c.z; a.w += c.w;
        out4[g] = a;
    }
}

extern "C" void kernel_launch(void* const* d_in, const int* in_sizes, int n_in,
                              void* d_out, int out_size, void* d_ws, size_t ws_size,
                              hipStream_t stream) {
    const float* self_t = (const float*)d_in[0];   // N*D fp32
    const int*   index  = (const int*)d_in[1];     // M*D int32
    const float* upd    = (const float*)d_in[2];   // M*D fp32
    float* out = (float*)d_out;

    const int nd = out_size;      // N*D
    const int md = in_sizes[1];   // M*D
    const int nrows = nd / DCOLS;
    const int nbins = (nrows + RB - 1) / RB;       // row-bins (782)
    int n4 = md / 4;
    int nblk = (n4 + CHUNK4 - 1) / CHUNK4;

    u32* total = (u32*)d_ws;                       // 2048 u32
    u32* start = total + 2048;                     // 2048 u32
    u16* mat   = (u16*)((char*)d_ws + MAT_OFF);    // nblk*2048 u16
    u64* pairs = (u64*)((char*)d_ws + PAIRS_OFF);  // md pairs

    size_t need = (size_t)PAIRS_OFF + (size_t)md * 8;
    bool shape_ok = (2 * nbins <= NBINP) && (nblk <= 1024) && !(md & 3) && !(nd & 3) &&
                    (md % DCOLS == 0) && (nd % DCOLS == 0);

    if (shape_ok && ws_size >= need) {
        hist_blocks<<<nblk, 256, 0, stream>>>((const int4*)index, mat, n4);
        scan_blocks<<<NBINP, 64, 0, stream>>>(mat, total, nblk);
        scan_binbases<<<1, 1024, 0, stream>>>(total, start);
        scatter_det2<<<nblk, 256, 0, stream>>>((const int4*)index, (const float4*)upd,
                                               mat, start, pairs, n4);
        apply_full<<<2 * nbins, 1024, 0, stream>>>((const float4*)self_t, pairs, start,
                                                   total, (float4*)out, nrows);
    } else {
        copy_f4<<<2048, 256, 0, stream>>>((const float4*)self_t, (float4*)out, nd / 4);
        scatter_add4<<<4096, 256, 0, stream>>>((const int4*)index, (const float4*)upd, out, md / 4);
    }
}

// Round 9
// 199.946 us; speedup vs baseline: 1.1972x; 1.1972x over previous
//
#include <hip/hip_runtime.h>

#define DCOLS 256
#define RB 128               // rows per bin
#define NBINP 1024           // padded bin count (actual 782)
#define MAT_OFF 16384
#define MAT_CAP (4u<<20)
#define PAIRS_OFF (MAT_OFF + MAT_CAP)
#define BLK4 1024            // int4 per sub-chunk (4096 elements)
#define SUBS 4
#define CHUNK4 (BLK4 * SUBS) // 16384 elements per block

typedef unsigned int u32;
typedef unsigned long long u64;

// ---------------- fallback path ----------------
__global__ void copy_f4(const float4* __restrict__ src, float4* __restrict__ dst, int n4) {
    int i = blockIdx.x * blockDim.x + threadIdx.x;
    int stride = gridDim.x * blockDim.x;
    for (; i < n4; i += stride) dst[i] = src[i];
}

__global__ void scatter_add4(const int4* __restrict__ index,
                             const float4* __restrict__ upd,
                             float* __restrict__ out, int n4) {
    int i = blockIdx.x * blockDim.x + threadIdx.x;
    int stride = gridDim.x * blockDim.x;
    for (; i < n4; i += stride) {
        int4 idx  = index[i];
        float4 u  = upd[i];
        int j = (i << 2) & (DCOLS - 1);
        atomicAdd(&out[idx.x * DCOLS + j + 0], u.x);
        atomicAdd(&out[idx.y * DCOLS + j + 1], u.y);
        atomicAdd(&out[idx.z * DCOLS + j + 2], u.z);
        atomicAdd(&out[idx.w * DCOLS + j + 3], u.w);
    }
}

// ---------------- K1: per-block histogram -> mat[blk][bin] ----------
__global__ void __launch_bounds__(256) hist_blocks(const int4* __restrict__ idx4,
                                                   u32* __restrict__ mat, int n4) {
    __shared__ u32 hist[NBINP];
    int t = threadIdx.x;
    int b0 = blockIdx.x * CHUNK4;
    for (int i = t; i < NBINP; i += 256) hist[i] = 0;
    __syncthreads();
#pragma unroll
    for (int k = 0; k < 16; ++k) {
        int p = b0 + t + 256 * k;
        if (p < n4) {
            int4 v = idx4[p];
            atomicAdd(&hist[((u32)v.x) >> 7], 1u);
            atomicAdd(&hist[((u32)v.y) >> 7], 1u);
            atomicAdd(&hist[((u32)v.z) >> 7], 1u);
            atomicAdd(&hist[((u32)v.w) >> 7], 1u);
        }
    }
    __syncthreads();
    u32 base = (u32)blockIdx.x * NBINP;
    for (int i = t; i < NBINP; i += 256) mat[base + i] = hist[i];
}

// ---------------- K2: one wave per bin, exclusive scan over blocks ----
__global__ void __launch_bounds__(64) scan_blocks(u32* __restrict__ mat,
                                                  u32* __restrict__ total, int nblk) {
    int bin = blockIdx.x;
    int lane = threadIdx.x;
    u32 carry = 0;
    int rounds = (nblk + 63) / 64;
    for (int r = 0; r < rounds; ++r) {
        int blk = r * 64 + lane;
        u32 v = (blk < nblk) ? mat[(u32)blk * NBINP + bin] : 0u;
        u32 incl = v;
#pragma unroll
        for (int d = 1; d < 64; d <<= 1) {
            u32 y = __shfl_up(incl, (unsigned)d, 64);
            if (lane >= d) incl += y;
        }
        if (blk < nblk) mat[(u32)blk * NBINP + bin] = carry + incl - v;
        carry += (u32)__shfl(incl, 63, 64);
    }
    if (lane == 0) total[bin] = carry;
}

// ---------------- K2b: exclusive scan of bin totals ----------
__global__ void scan_binbases(const u32* __restrict__ total, u32* __restrict__ start) {
    __shared__ u32 tmp[1024];
    int t = threadIdx.x;
    u32 v = total[t];
    tmp[t] = v;
    __syncthreads();
    for (int off = 1; off < 1024; off <<= 1) {
        u32 a = (t >= off) ? tmp[t - off] : 0u;
        __syncthreads();
        tmp[t] += a;
        __syncthreads();
    }
    start[t] = tmp[t] - v;
}

// ---------------- K3: deterministic scatter, register bin-bases ----------
// LDS = hist 4K + bias 4K + stage 32K = 40960 B exactly -> 4 blocks/CU.
__global__ void __launch_bounds__(256, 4) scatter_det3(const int4* __restrict__ idx4,
                                                       const float4* __restrict__ upd4,
                                                       const u32* __restrict__ mat,
                                                       const u32* __restrict__ start,
                                                       u64* __restrict__ pairs, int n4) {
    __shared__ u32 hist[NBINP];     // counts, then staging cursors
    __shared__ u32 bias[NBINP];     // basep - excl per bin; [1020..1023] = wave totals
    __shared__ u64 stage[4096];     // 32 KB

    int t = threadIdx.x;
    int lane = t & 63, wid = t >> 6;
    int b0 = blockIdx.x * CHUNK4;
    u32 mbase = (u32)blockIdx.x * NBINP;

    // register-resident dest bases for owned bins 4t..4t+3
    uint4 s4 = ((const uint4*)start)[t];
    uint4 m4 = ((const uint4*)(mat + mbase))[t];
    u32 bp[4] = { s4.x + m4.x, s4.y + m4.y, s4.z + m4.z, s4.w + m4.w };

    int4 iv[4]; float4 uv[4]; int4 ivn[4]; float4 uvn[4];
#pragma unroll
    for (int k = 0; k < 4; ++k) {
        int p = b0 + t + 256 * k;
        if (p < n4) { iv[k] = idx4[p]; uv[k] = upd4[p]; }
    }
    for (int i = t; i < NBINP; i += 256) hist[i] = 0;
    __syncthreads();

    for (int s = 0; s < SUBS; ++s) {
        int sbase = b0 + s * BLK4;
        // histogram this sub
#pragma unroll
        for (int k = 0; k < 4; ++k) {
            int p = sbase + t + 256 * k;
            if (p < n4) {
                atomicAdd(&hist[((u32)iv[k].x) >> 7], 1u);
                atomicAdd(&hist[((u32)iv[k].y) >> 7], 1u);
                atomicAdd(&hist[((u32)iv[k].z) >> 7], 1u);
                atomicAdd(&hist[((u32)iv[k].w) >> 7], 1u);
            }
        }
        __syncthreads();                                  // (A)
        // prefetch next sub (latency hides under scan+stage)
        if (s < SUBS - 1) {
#pragma unroll
            for (int k = 0; k < 4; ++k) {
                int p = sbase + BLK4 + t + 256 * k;
                if (p < n4) { ivn[k] = idx4[p]; uvn[k] = upd4[p]; }
            }
        }
        // exclusive scan of sub counts (own bins only -> no cross-thread hazard)
        u32 c0 = hist[4 * t + 0], c1 = hist[4 * t + 1];
        u32 c2 = hist[4 * t + 2], c3 = hist[4 * t + 3];
        u32 tsum = c0 + c1 + c2 + c3;
        u32 incl = tsum;
#pragma unroll
        for (int d = 1; d < 64; d <<= 1) {
            u32 y = __shfl_up(incl, (unsigned)d, 64);
            if (lane >= d) incl += y;
        }
        if (lane == 63) bias[1020 + wid] = incl;          // bins 1020..1023 always empty
        __syncthreads();                                  // (B)
        u32 woff = 0;
#pragma unroll
        for (int w = 0; w < 4; ++w) woff += (w < wid) ? bias[1020 + w] : 0u;
        u32 e = woff + incl - tsum;
        u32 cc[4] = {c0, c1, c2, c3};
#pragma unroll
        for (int j = 0; j < 4; ++j) {
            u32 bin = 4u * (u32)t + (u32)j;
            if (cc[j]) {
                bias[bin] = bp[j] - e;    // unsigned wrap ok: flush adds i >= e
                hist[bin] = e;            // staging cursor
                bp[j] += cc[j];
            }
            e += cc[j];
        }
        __syncthreads();                                  // (C)
        // stage bin-sorted
        u32 colbase = (4u * (u32)t) & 255u;
#pragma unroll
        for (int k = 0; k < 4; ++k) {
            int p = sbase + t + 256 * k;
            if (p >= n4) continue;
            int rows[4] = {iv[k].x, iv[k].y, iv[k].z, iv[k].w};
            float vals[4] = {uv[k].x, uv[k].y, uv[k].z, uv[k].w};
#pragma unroll
            for (int c = 0; c < 4; ++c) {
                u32 row = (u32)rows[c];
                u32 slot = atomicAdd(&hist[row >> 7], 1u);
                stage[slot] = ((u64)__float_as_uint(vals[c]) << 32)
                            | ((u64)row << 8) | (u64)(colbase + (u32)c);
            }
        }
        __syncthreads();                                  // (D)
        // coalesced flush + zero hist for next sub (disjoint arrays)
        int sv = n4 - sbase; if (sv > BLK4) sv = BLK4; if (sv < 0) sv = 0;
        int scount = 4 * sv;
        for (int i = t; i < scount; i += 256) {
            u64 pr = stage[i];
            u32 rc  = (u32)pr & 0x1ffffffu;   // row<<8 | col
            u32 row = rc >> 8;
            u32 bin = row >> 7;
            u32 d = bias[bin] + (u32)i;
            u32 key = ((row & 127u) << 8) | (rc & 255u);
            pairs[d] = (pr & 0xffffffff00000000ull) | (u64)key;
        }
        for (int i = t; i < NBINP; i += 256) hist[i] = 0;
        if (s < SUBS - 1) {
#pragma unroll
            for (int k = 0; k < 4; ++k) { iv[k] = ivn[k]; uv[k] = uvn[k]; }
        }
        __syncthreads();                                  // (E)
    }
}

// ---------------- K4: apply, two blocks per bin (column halves) ----------
#define APPLY_P(p) { u32 k_ = (u32)(p); \
    if (((k_ >> 7) & 1u) == half) \
        atomicAdd(&acc[((k_ >> 8) & 127u) * 128u + (k_ & 127u)], \
                  __uint_as_float((u32)((p) >> 32))); }

__global__ void __launch_bounds__(1024, 8) apply_half(const float4* __restrict__ self4,
                                                      const u64* __restrict__ pairs,
                                                      const u32* __restrict__ start,
                                                      const u32* __restrict__ total,
                                                      float4* __restrict__ out4, int nrows) {
    __shared__ float acc[RB * 128];   // 64 KB
    int t = threadIdx.x;
    int bin = blockIdx.x >> 1;
    u32 half = blockIdx.x & 1u;
    float4* acc4 = (float4*)acc;
    for (int i = t; i < RB * 32; i += 1024) acc4[i] = make_float4(0.f, 0.f, 0.f, 0.f);
    __syncthreads();

    u32 s = start[bin], e = s + total[bin];
    u32 i = s + (u32)t;
    for (; i + 3072u < e; i += 4096u) {
        u64 p0 = pairs[i];
        u64 p1 = pairs[i + 1024u];
        u64 p2 = pairs[i + 2048u];
        u64 p3 = pairs[i + 3072u];
        APPLY_P(p0); APPLY_P(p1); APPLY_P(p2); APPLY_P(p3);
    }
    for (; i < e; i += 1024u) { u64 p0 = pairs[i]; APPLY_P(p0); }
    __syncthreads();

    int r0 = bin * RB;
    int nr = nrows - r0; if (nr > RB) nr = RB;
    int tot4 = nr * 32;
    for (int i2 = t; i2 < tot4; i2 += 1024) {
        int r = i2 >> 5, c4 = i2 & 31;
        long g = (long)(r0 + r) * 64 + (long)(half * 32u) + c4;
        float4 a = self4[g];
        float4 c = acc4[(r << 5) + c4];
        a.x += c.x; a.y += c.y; a.z += c.z; a.w += c.w;
        out4[g] = a;
    }
}

extern "C" void kernel_launch(void* const* d_in, const int* in_sizes, int n_in,
                              void* d_out, int out_size, void* d_ws, size_t ws_size,
                              hipStream_t stream) {
    const float* self_t = (const float*)d_in[0];   // N*D fp32
    const int*   index  = (const int*)d_in[1];     // M*D int32
    const float* upd    = (const float*)d_in[2];   // M*D fp32
    float* out = (float*)d_out;

    const int nd = out_size;      // N*D
    const int md = in_sizes[1];   // M*D
    const int nrows = nd / DCOLS;
    const int nbins = (nrows + RB - 1) / RB;
    int n4 = md / 4;
    int nblk = (n4 + CHUNK4 - 1) / CHUNK4;

    u32* total = (u32*)d_ws;                       // 1024 u32
    u32* start = total + 1024;                     // 1024 u32
    u32* mat   = (u32*)((char*)d_ws + MAT_OFF);    // nblk*1024 u32
    u64* pairs = (u64*)((char*)d_ws + PAIRS_OFF);  // md pairs

    size_t need = (size_t)PAIRS_OFF + (size_t)md * 8;
    bool shape_ok = (nbins <= 1020) && (nblk <= 1024) && !(md & 3) && !(nd & 3) &&
                    (md % DCOLS == 0) && (nd % DCOLS == 0);

    if (shape_ok && ws_size >= need) {
        hist_blocks<<<nblk, 256, 0, stream>>>((const int4*)index, mat, n4);
        scan_blocks<<<NBINP, 64, 0, stream>>>(mat, total, nblk);
        scan_binbases<<<1, 1024, 0, stream>>>(total, start);
        scatter_det3<<<nblk, 256, 0, stream>>>((const int4*)index, (const float4*)upd,
                                               mat, start, pairs, n4);
        apply_half<<<2 * nbins, 1024, 0, stream>>>((const float4*)self_t, pairs, start,
                                                   total, (float4*)out, nrows);
    } else {
        copy_f4<<<2048, 256, 0, stream>>>((const float4*)self_t, (float4*)out, nd / 4);
        scatter_add4<<<4096, 256, 0, stream>>>((const int4*)index, (const float4*)upd, out, md / 4);
    }
}

// Round 10
// 185.377 us; speedup vs baseline: 1.2913x; 1.0786x over previous
//
#include <hip/hip_runtime.h>

#define DCOLS 256
#define RB 128               // rows per bin
#define NBINP 1024           // padded bin count (actual 782)
#define MAT_OFF 16384
#define MAT_CAP (4u<<20)
#define PAIRS_OFF (MAT_OFF + MAT_CAP)
#define SUB4 2048            // int4 per sub-chunk (8192 elements)
#define SUBS 2
#define CHUNK4 (SUB4 * SUBS) // 4096 int4 = 16384 elements per block

typedef unsigned int u32;
typedef unsigned long long u64;

// ---------------- fallback path ----------------
__global__ void copy_f4(const float4* __restrict__ src, float4* __restrict__ dst, int n4) {
    int i = blockIdx.x * blockDim.x + threadIdx.x;
    int stride = gridDim.x * blockDim.x;
    for (; i < n4; i += stride) dst[i] = src[i];
}

__global__ void scatter_add4(const int4* __restrict__ index,
                             const float4* __restrict__ upd,
                             float* __restrict__ out, int n4) {
    int i = blockIdx.x * blockDim.x + threadIdx.x;
    int stride = gridDim.x * blockDim.x;
    for (; i < n4; i += stride) {
        int4 idx  = index[i];
        float4 u  = upd[i];
        int j = (i << 2) & (DCOLS - 1);
        atomicAdd(&out[idx.x * DCOLS + j + 0], u.x);
        atomicAdd(&out[idx.y * DCOLS + j + 1], u.y);
        atomicAdd(&out[idx.z * DCOLS + j + 2], u.z);
        atomicAdd(&out[idx.w * DCOLS + j + 3], u.w);
    }
}

// ---------------- K1: per-block histogram -> mat[blk][bin] ----------
__global__ void __launch_bounds__(256) hist_blocks(const int4* __restrict__ idx4,
                                                   u32* __restrict__ mat, int n4) {
    __shared__ u32 hist[NBINP];
    int t = threadIdx.x;
    int b0 = blockIdx.x * CHUNK4;
    for (int i = t; i < NBINP; i += 256) hist[i] = 0;
    __syncthreads();
#pragma unroll
    for (int k = 0; k < 16; ++k) {
        int p = b0 + t + 256 * k;
        if (p < n4) {
            int4 v = idx4[p];
            atomicAdd(&hist[((u32)v.x) >> 7], 1u);
            atomicAdd(&hist[((u32)v.y) >> 7], 1u);
            atomicAdd(&hist[((u32)v.z) >> 7], 1u);
            atomicAdd(&hist[((u32)v.w) >> 7], 1u);
        }
    }
    __syncthreads();
    u32 base = (u32)blockIdx.x * NBINP;
    for (int i = t; i < NBINP; i += 256) mat[base + i] = hist[i];
}

// ---------------- K2: one wave per bin, exclusive scan over blocks ----
__global__ void __launch_bounds__(64) scan_blocks(u32* __restrict__ mat,
                                                  u32* __restrict__ total, int nblk) {
    int bin = blockIdx.x;
    int lane = threadIdx.x;
    u32 carry = 0;
    int rounds = (nblk + 63) / 64;
    for (int r = 0; r < rounds; ++r) {
        int blk = r * 64 + lane;
        u32 v = (blk < nblk) ? mat[(u32)blk * NBINP + bin] : 0u;
        u32 incl = v;
#pragma unroll
        for (int d = 1; d < 64; d <<= 1) {
            u32 y = __shfl_up(incl, (unsigned)d, 64);
            if (lane >= d) incl += y;
        }
        if (blk < nblk) mat[(u32)blk * NBINP + bin] = carry + incl - v;
        carry += (u32)__shfl(incl, 63, 64);
    }
    if (lane == 0) total[bin] = carry;
}

// ---------------- K2b: exclusive scan of bin totals ----------
__global__ void scan_binbases(const u32* __restrict__ total, u32* __restrict__ start) {
    __shared__ u32 tmp[1024];
    int t = threadIdx.x;
    u32 v = total[t];
    tmp[t] = v;
    __syncthreads();
    for (int off = 1; off < 1024; off <<= 1) {
        u32 a = (t >= off) ? tmp[t - off] : 0u;
        __syncthreads();
        tmp[t] += a;
        __syncthreads();
    }
    start[t] = tmp[t] - v;
}

// ---------------- K3: deterministic scatter, 512 thr, 64KB stage ----------
// LDS = hist 4K + bias 4K + stage 64K = 73728 B -> 2 blocks/CU (16 waves).
// Runs ~10.5 pairs per bin per flush (stage holds 8192 pairs).
__global__ void __launch_bounds__(512, 4) scatter_det4(const int4* __restrict__ idx4,
                                                       const float4* __restrict__ upd4,
                                                       const u32* __restrict__ mat,
                                                       const u32* __restrict__ start,
                                                       u64* __restrict__ pairs, int n4) {
    __shared__ u32 hist[NBINP];     // counts, then staging cursors
    __shared__ u32 bias[NBINP];     // basep - excl per bin; [1008..1015] = wave totals
    __shared__ u64 stage[SUB4 * 4]; // 64 KB

    int t = threadIdx.x;
    int lane = t & 63, wid = t >> 6;   // 8 waves
    int b0 = blockIdx.x * CHUNK4;
    u32 mbase = (u32)blockIdx.x * NBINP;

    // register-resident dest bases for owned bins 2t, 2t+1
    uint2 s2 = ((const uint2*)start)[t];
    uint2 m2 = ((const uint2*)(mat + mbase))[t];
    u32 bp[2] = { s2.x + m2.x, s2.y + m2.y };

    int4 iv[4]; float4 uv[4]; int4 ivn[4]; float4 uvn[4];
#pragma unroll
    for (int k = 0; k < 4; ++k) {
        int p = b0 + t + 512 * k;
        if (p < n4) { iv[k] = idx4[p]; uv[k] = upd4[p]; }
    }
    for (int i = t; i < NBINP; i += 512) hist[i] = 0;
    __syncthreads();

    for (int s = 0; s < SUBS; ++s) {
        int sbase = b0 + s * SUB4;
        // histogram this sub
#pragma unroll
        for (int k = 0; k < 4; ++k) {
            int p = sbase + t + 512 * k;
            if (p < n4) {
                atomicAdd(&hist[((u32)iv[k].x) >> 7], 1u);
                atomicAdd(&hist[((u32)iv[k].y) >> 7], 1u);
                atomicAdd(&hist[((u32)iv[k].z) >> 7], 1u);
                atomicAdd(&hist[((u32)iv[k].w) >> 7], 1u);
            }
        }
        __syncthreads();                                  // (A)
        // prefetch next sub (latency hides under scan+stage)
        if (s < SUBS - 1) {
#pragma unroll
            for (int k = 0; k < 4; ++k) {
                int p = sbase + SUB4 + t + 512 * k;
                if (p < n4) { ivn[k] = idx4[p]; uvn[k] = upd4[p]; }
            }
        }
        // exclusive scan of sub counts: thread t owns bins 2t, 2t+1
        u32 c0 = hist[2 * t + 0], c1 = hist[2 * t + 1];
        u32 tsum = c0 + c1;
        u32 incl = tsum;
#pragma unroll
        for (int d = 1; d < 64; d <<= 1) {
            u32 y = __shfl_up(incl, (unsigned)d, 64);
            if (lane >= d) incl += y;
        }
        if (lane == 63) bias[1008 + wid] = incl;          // bins 1008..1015 always empty
        __syncthreads();                                  // (B)
        u32 woff = 0;
#pragma unroll
        for (int w = 0; w < 8; ++w) woff += (w < wid) ? bias[1008 + w] : 0u;
        u32 e = woff + incl - tsum;
        u32 cc[2] = {c0, c1};
#pragma unroll
        for (int j = 0; j < 2; ++j) {
            u32 bin = 2u * (u32)t + (u32)j;
            if (cc[j]) {
                bias[bin] = bp[j] - e;    // unsigned wrap ok: flush adds i >= e
                hist[bin] = e;            // staging cursor
                bp[j] += cc[j];
            }
            e += cc[j];
        }
        __syncthreads();                                  // (C)
        // stage bin-sorted
        u32 colbase = (4u * (u32)t) & 255u;
#pragma unroll
        for (int k = 0; k < 4; ++k) {
            int p = sbase + t + 512 * k;
            if (p >= n4) continue;
            int rows[4] = {iv[k].x, iv[k].y, iv[k].z, iv[k].w};
            float vals[4] = {uv[k].x, uv[k].y, uv[k].z, uv[k].w};
#pragma unroll
            for (int c = 0; c < 4; ++c) {
                u32 row = (u32)rows[c];
                u32 slot = atomicAdd(&hist[row >> 7], 1u);
                stage[slot] = ((u64)__float_as_uint(vals[c]) << 32)
                            | ((u64)row << 8) | (u64)(colbase + (u32)c);
            }
        }
        __syncthreads();                                  // (D)
        // coalesced flush + zero hist for next sub (disjoint arrays)
        int sv = n4 - sbase; if (sv > SUB4) sv = SUB4; if (sv < 0) sv = 0;
        int scount = 4 * sv;
        for (int i = t; i < scount; i += 512) {
            u64 pr = stage[i];
            u32 rc  = (u32)pr & 0x1ffffffu;   // row<<8 | col
            u32 row = rc >> 8;
            u32 bin = row >> 7;
            u32 d = bias[bin] + (u32)i;
            u32 key = ((row & 127u) << 8) | (rc & 255u);
            pairs[d] = (pr & 0xffffffff00000000ull) | (u64)key;
        }
        for (int i = t; i < NBINP; i += 512) hist[i] = 0;
        if (s < SUBS - 1) {
#pragma unroll
            for (int k = 0; k < 4; ++k) { iv[k] = ivn[k]; uv[k] = uvn[k]; }
        }
        __syncthreads();                                  // (E)
    }
}

// ---------------- K4: apply, two blocks per bin (column halves) ----------
#define APPLY_P(p) { u32 k_ = (u32)(p); \
    if (((k_ >> 7) & 1u) == half) \
        atomicAdd(&acc[((k_ >> 8) & 127u) * 128u + (k_ & 127u)], \
                  __uint_as_float((u32)((p) >> 32))); }

__global__ void __launch_bounds__(1024, 8) apply_half(const float4* __restrict__ self4,
                                                      const u64* __restrict__ pairs,
                                                      const u32* __restrict__ start,
                                                      const u32* __restrict__ total,
                                                      float4* __restrict__ out4, int nrows) {
    __shared__ float acc[RB * 128];   // 64 KB
    int t = threadIdx.x;
    int bin = blockIdx.x >> 1;
    u32 half = blockIdx.x & 1u;
    float4* acc4 = (float4*)acc;
    for (int i = t; i < RB * 32; i += 1024) acc4[i] = make_float4(0.f, 0.f, 0.f, 0.f);
    __syncthreads();

    u32 s = start[bin], e = s + total[bin];
    u32 i = s + (u32)t;
    for (; i + 3072u < e; i += 4096u) {
        u64 p0 = pairs[i];
        u64 p1 = pairs[i + 1024u];
        u64 p2 = pairs[i + 2048u];
        u64 p3 = pairs[i + 3072u];
        APPLY_P(p0); APPLY_P(p1); APPLY_P(p2); APPLY_P(p3);
    }
    for (; i < e; i += 1024u) { u64 p0 = pairs[i]; APPLY_P(p0); }
    __syncthreads();

    int r0 = bin * RB;
    int nr = nrows - r0; if (nr > RB) nr = RB;
    int tot4 = nr * 32;
    for (int i2 = t; i2 < tot4; i2 += 1024) {
        int r = i2 >> 5, c4 = i2 & 31;
        long g = (long)(r0 + r) * 64 + (long)(half * 32u) + c4;
        float4 a = self4[g];
        float4 c = acc4[(r << 5) + c4];
        a.x += c.x; a.y += c.y; a.z += c.z; a.w += c.w;
        out4[g] = a;
    }
}

extern "C" void kernel_launch(void* const* d_in, const int* in_sizes, int n_in,
                              void* d_out, int out_size, void* d_ws, size_t ws_size,
                              hipStream_t stream) {
    const float* self_t = (const float*)d_in[0];   // N*D fp32
    const int*   index  = (const int*)d_in[1];     // M*D int32
    const float* upd    = (const float*)d_in[2];   // M*D fp32
    float* out = (float*)d_out;

    const int nd = out_size;      // N*D
    const int md = in_sizes[1];   // M*D
    const int nrows = nd / DCOLS;
    const int nbins = (nrows + RB - 1) / RB;
    int n4 = md / 4;
    int nblk = (n4 + CHUNK4 - 1) / CHUNK4;

    u32* total = (u32*)d_ws;                       // 1024 u32
    u32* start = total + 1024;                     // 1024 u32
    u32* mat   = (u32*)((char*)d_ws + MAT_OFF);    // nblk*1024 u32
    u64* pairs = (u64*)((char*)d_ws + PAIRS_OFF);  // md pairs

    size_t need = (size_t)PAIRS_OFF + (size_t)md * 8;
    bool shape_ok = (nbins <= 1008) && (nblk <= 1024) && !(md & 3) && !(nd & 3) &&
                    (md % DCOLS == 0) && (nd % DCOLS == 0);

    if (shape_ok && ws_size >= need) {
        hist_blocks<<<nblk, 256, 0, stream>>>((const int4*)index, mat, n4);
        scan_blocks<<<NBINP, 64, 0, stream>>>(mat, total, nblk);
        scan_binbases<<<1, 1024, 0, stream>>>(total, start);
        scatter_det4<<<nblk, 512, 0, stream>>>((const int4*)index, (const float4*)upd,
                                               mat, start, pairs, n4);
        apply_half<<<2 * nbins, 1024, 0, stream>>>((const float4*)self_t, pairs, start,
                                                   total, (float4*)out, nrows);
    } else {
        copy_f4<<<2048, 256, 0, stream>>>((const float4*)self_t, (float4*)out, nd / 4);
        scatter_add4<<<4096, 256, 0, stream>>>((const int4*)index, (const float4*)upd, out, md / 4);
    }
}